// Round 10
// baseline (1332.363 us; speedup 1.0000x reference)
//
#include <hip/hip_runtime.h>

// DecoderWithAttention: B=16, T=32, F=8, S_ENC=256, H=512, L=2.
// R16 = R15 (proven 822us) minus ONE sync: hidP rides the h1 sync as linear
// partials (minimal diff; R14's failed version changed 5 things at once).
//  - phase 3 producers also compute hPP = whidT[s-slice] @ h1new-slice
//    (32 dot2/thread, 32KB L2-hot slice) and cstore 512 f32; same tag-3.
//  - tag-3 gather additionally sums 16 hPP partials (32 pipelined cloads)
//    into L_HIDP. Phase 0 + tag-0 deleted from the loop.
//  - t=0 bootstrap: same partial+tag0 path once before the loop.
//  - all else byte-identical to R15 (poll discipline, fences, slots).

namespace {
constexpr int NTHR = 256, NBLK = 256;

// ws u32/float offsets. memset covers [0, 32768) bytes (tag region).
// tags[(b*16+s)*32 + phase]; phases 0..3. grid counter at u32 8180.
constexpr int OFF_WNS   = 8192;       // [256][256] u32 normalized wp f16x2
constexpr int OFF_LS    = 73728;      // [256] f32 per-slice L
constexpr int OFF_H0S   = 73984;      // [256][16] u32 h0new slices
constexpr int OFF_H1S   = 78080;      // [256][16] u32 h1new slices
constexpr int OFF_HPP   = 82176;      // [256][512] f32 hidP partials
constexpr int OFF_AEH   = 213248;     // [512][256] u32 attn_W[:,512:]
constexpr int OFF_WHIDT = 344320;     // [256][512] u32 whid transposed (kp-major)
constexpr int OFF_WIH0  = 475392;     // [1536][260] u32
constexpr int OFF_WHH0  = 874752;     // [1536][256] u32
constexpr int OFF_WIH1  = 1267968;    // [1536][256] u32
constexpr int OFF_WHH1  = 1661184;    // [1536][256] u32
constexpr int OFF_ENCP  = 2054400;    // [4096][256] u32
// end = 3,102,976 floats = 12.41 MB

// LDS float/u32 offsets. P2 prologue staging uses [0..8192).
constexpr int L_H1   = 0;      // [256] u32 h1(t) f16x2 full
constexpr int L_H0   = 256;    // [256] u32 h0(t) f16x2 full
constexpr int L_HIDP = 512;    // [512] f32
constexpr int L_ES   = 1024;   // [16] exp(score) (reused for out staging)
constexpr int L_HX   = 1040;   // [264] u32: xin(4) | weighted(256) | pad(4)
constexpr int L_AX   = 1304;   // [96]
constexpr int L_AH   = 1400;   // [96]
constexpr int L_BIH0 = 1496, L_BHH0 = 1592, L_BIH1 = 1688, L_BHH1 = 1784;  // [96]
constexpr int L_VW   = 1880;   // [512]
constexpr int L_XINL = 2392;   // [8]
constexpr int L_LL   = 2400;   // [16] gathered L_s
constexpr int L_H1S  = 2416;   // [16] u32 own h1new slice staging
constexpr int LDS_FLOATS = 8192;
}  // namespace

typedef _Float16 h2 __attribute__((ext_vector_type(2)));
union U32H { unsigned u; h2 h; };

__device__ __forceinline__ float dot2(unsigned a, unsigned b, float acc) {
    U32H ua, ub; ua.u = a; ub.u = b;
#if __has_builtin(__builtin_amdgcn_fdot2)
    return __builtin_amdgcn_fdot2(ua.h, ub.h, acc, false);
#else
    return acc + (float)ua.h.x * (float)ub.h.x + (float)ua.h.y * (float)ub.h.y;
#endif
}
__device__ __forceinline__ unsigned packh2(float a, float b) {
    U32H u; u.h = h2{(_Float16)a, (_Float16)b}; return u.u;
}
__device__ __forceinline__ float fsig(float x) { return 1.0f / (1.0f + __expf(-x)); }
__device__ __forceinline__ float ftanhf(float x) {
    float e = __expf(2.0f * x);
    return 1.0f - 2.0f / (e + 1.0f);
}
// Uncached per-access comm ops (sc0 sc1 -> coherence point).
__device__ __forceinline__ float cload(const float* p) {
    return __hip_atomic_load(p, __ATOMIC_RELAXED, __HIP_MEMORY_SCOPE_SYSTEM);
}
__device__ __forceinline__ void cstore(float* p, float v) {
    __hip_atomic_store(p, v, __ATOMIC_RELAXED, __HIP_MEMORY_SCOPE_SYSTEM);
}
__device__ __forceinline__ unsigned ucload(const unsigned* p) {
    return __hip_atomic_load(p, __ATOMIC_RELAXED, __HIP_MEMORY_SCOPE_SYSTEM);
}
__device__ __forceinline__ void ucstore(unsigned* p, unsigned v) {
    __hip_atomic_store(p, v, __ATOMIC_RELAXED, __HIP_MEMORY_SCOPE_SYSTEM);
}

// Prologue barrier: one agent-scope wbl2 (release) / inv (acquire) per block.
__device__ __forceinline__ void bar_sync_flush(unsigned* cnt, unsigned target) {
    __syncthreads();
    if (threadIdx.x == 0) {
        __builtin_amdgcn_fence(__ATOMIC_RELEASE, "agent");
        __hip_atomic_fetch_add(cnt, 1u, __ATOMIC_RELAXED, __HIP_MEMORY_SCOPE_SYSTEM);
        while (__hip_atomic_load(cnt, __ATOMIC_RELAXED, __HIP_MEMORY_SCOPE_SYSTEM) < target)
            __builtin_amdgcn_s_sleep(8);
        __builtin_amdgcn_fence(__ATOMIC_ACQUIRE, "agent");
    }
    __syncthreads();
}

__global__ __launch_bounds__(NTHR) void decoder_kernel(
    const float* __restrict__ target, const float* __restrict__ hidden0,
    const float* __restrict__ enc, const float* __restrict__ attn_W,
    const float* __restrict__ attn_b, const float* __restrict__ v_w,
    const float* __restrict__ Wih0, const float* __restrict__ Whh0,
    const float* __restrict__ bih0, const float* __restrict__ bhh0,
    const float* __restrict__ Wih1, const float* __restrict__ Whh1,
    const float* __restrict__ bih1, const float* __restrict__ bhh1,
    const float* __restrict__ outW, const float* __restrict__ outBias,
    float* __restrict__ out, float* __restrict__ ws) {
    const int tid = threadIdx.x, bid = blockIdx.x;
    const int b = bid >> 4, s = bid & 15;   // group (batch) / slice
    unsigned* tags = (unsigned*)ws;
    unsigned* gridCnt = (unsigned*)ws + 8180;

    unsigned* wnS = (unsigned*)(ws + OFF_WNS);
    float* lS = ws + OFF_LS;
    unsigned* h0S = (unsigned*)(ws + OFF_H0S);
    unsigned* h1S = (unsigned*)(ws + OFF_H1S);
    float* hPP = ws + OFF_HPP;
    unsigned* aehU   = (unsigned*)(ws + OFF_AEH);
    unsigned* whidTU = (unsigned*)(ws + OFF_WHIDT);
    unsigned* wih0U = (unsigned*)(ws + OFF_WIH0);
    unsigned* whh0U = (unsigned*)(ws + OFF_WHH0);
    unsigned* wih1U = (unsigned*)(ws + OFF_WIH1);
    unsigned* whh1U = (unsigned*)(ws + OFF_WHH1);
    unsigned* encpU = (unsigned*)(ws + OFF_ENCP);

    __shared__ __align__(16) float lds[LDS_FLOATS];
    unsigned* ldsU = (unsigned*)lds;
    const int gtid = bid * NTHR + tid;

    // ===================== P1: f16 pack (plain stores) ========================
    for (int i = gtid; i < 131072; i += NBLK * NTHR) {
        const int jr = i >> 8, p = i & 255;
        aehU[i] = packh2(attn_W[jr * 1024 + 512 + 2 * p], attn_W[jr * 1024 + 513 + 2 * p]);
    }
    for (int i = gtid; i < 131072; i += NBLK * NTHR) {
        const int kp = i >> 9, r = i & 511;  // transposed: [kp][r]
        whidTU[i] = packh2(attn_W[r * 1024 + 2 * kp], attn_W[r * 1024 + 2 * kp + 1]);
    }
    for (int i = gtid; i < 399360; i += NBLK * NTHR)
        wih0U[i] = packh2(Wih0[2 * i], Wih0[2 * i + 1]);
    for (int i = gtid; i < 393216; i += NBLK * NTHR) {
        whh0U[i] = packh2(Whh0[2 * i], Whh0[2 * i + 1]);
        wih1U[i] = packh2(Wih1[2 * i], Wih1[2 * i + 1]);
        whh1U[i] = packh2(Whh1[2 * i], Whh1[2 * i + 1]);
    }
    bar_sync_flush(gridCnt, NBLK);  // one wbl2/inv per block

    // ===================== P2: enc_proj for own (b, 16 s), raw f32 enc ========
    {
        for (int i = 0; i < 32; ++i) {
            const int idx = tid + i * 256;
            lds[idx] = enc[(b * 256 + s * 16) * 512 + idx];  // 16 s x 512
        }
        __syncthreads();
        float a0[16], a1[16];
        const float bb0 = attn_b[2 * tid], bb1 = attn_b[2 * tid + 1];
#pragma unroll
        for (int sl = 0; sl < 16; ++sl) { a0[sl] = bb0; a1[sl] = bb1; }
        const unsigned* w0 = &aehU[(2 * tid) * 256];
        const unsigned* w1 = &aehU[(2 * tid + 1) * 256];
        for (int p = 0; p < 256; ++p) {
            const unsigned ww0 = w0[p], ww1 = w1[p];
#pragma unroll
            for (int sl = 0; sl < 16; ++sl) {
                const unsigned epk = packh2(lds[sl * 512 + 2 * p], lds[sl * 512 + 2 * p + 1]);
                a0[sl] = dot2(epk, ww0, a0[sl]);
                a1[sl] = dot2(epk, ww1, a1[sl]);
            }
        }
        for (int sl = 0; sl < 16; ++sl)  // self-read only (plain, same-XCD L2)
            encpU[(b * 256 + s * 16 + sl) * 256 + tid] = packh2(a0[sl], a1[sl]);
        __syncthreads();
    }

    // ===================== P3: pin biases + v_w in LDS ========================
    if (tid < 96) {
        const int grow = (tid >> 5) * 512 + s * 32 + (tid & 31);
        lds[L_BIH0 + tid] = bih0[grow]; lds[L_BHH0 + tid] = bhh0[grow];
        lds[L_BIH1 + tid] = bih1[grow]; lds[L_BHH1 + tid] = bhh1[grow];
    }
    lds[L_VW + tid] = v_w[tid];
    lds[L_VW + 256 + tid] = v_w[256 + tid];
    __syncthreads();

    // initial state (t=0): h0/h1 full + x_in from target
    ldsU[L_H1 + tid] = packh2(hidden0[8192 + b * 512 + 2 * tid],
                              hidden0[8192 + b * 512 + 2 * tid + 1]);
    ldsU[L_H0 + tid] = packh2(hidden0[b * 512 + 2 * tid], hidden0[b * 512 + 2 * tid + 1]);
    if (tid < 8) lds[L_XINL + tid] = target[b * 256 + tid];
    if (tid < 4) ldsU[L_HX + 260 + tid] = 0u;  // permanent zero tail pad
    __syncthreads();

    // ---- t=0 bootstrap: hidP(0) via partials + tag0 (once) ----
    {
        float p0 = 0.f, p1 = 0.f;
#pragma unroll
        for (int k = 0; k < 16; ++k) {
            const unsigned hp = ldsU[L_H1 + s * 16 + k];
            p0 = dot2(whidTU[(s * 16 + k) * 512 + tid], hp, p0);
            p1 = dot2(whidTU[(s * 16 + k) * 512 + 256 + tid], hp, p1);
        }
        cstore(&hPP[(b * 16 + s) * 512 + tid], p0);
        cstore(&hPP[(b * 16 + s) * 512 + 256 + tid], p1);
        __syncthreads();
        if (tid == 0) ucstore(&tags[(b * 16 + s) * 32 + 0], 1u);
        if (tid < 16) {
            const unsigned* tg = &tags[(b * 16 + tid) * 32 + 0];
            while (ucload(tg) < 1u) __builtin_amdgcn_s_sleep(1);
        }
        __syncthreads();
        __builtin_amdgcn_fence(__ATOMIC_ACQUIRE, "workgroup");
        float a0 = 0.f, a1 = 0.f;
#pragma unroll
        for (int sp = 0; sp < 16; ++sp) {
            a0 += cload(&hPP[(b * 16 + sp) * 512 + tid]);
            a1 += cload(&hPP[(b * 16 + sp) * 512 + 256 + tid]);
        }
        lds[L_HIDP + tid] = a0;
        lds[L_HIDP + 256 + tid] = a1;
        __syncthreads();
    }

    // ===================== main recurrence (3 syncs/step) =====================
    for (int t = 0; t < 32; ++t) {
        const unsigned tgt = (unsigned)(t + 1);

        // ---- phase 1: energy own 16 s + exp + NORMALIZED f16 wp + L ----
        {
            const int sloc = tid >> 4, sub = tid & 15;
            const unsigned* ep = &encpU[(b * 256 + s * 16 + sloc) * 256];
            float acc = 0.f;
#pragma unroll 4
            for (int k2 = 0; k2 < 16; ++k2) {
                const int p = k2 * 16 + sub;
                U32H u; u.u = ep[p];
                acc += lds[L_VW + 2 * p] * ftanhf((float)u.h.x + lds[L_HIDP + 2 * p]);
                acc += lds[L_VW + 2 * p + 1] * ftanhf((float)u.h.y + lds[L_HIDP + 2 * p + 1]);
            }
            acc += __shfl_down(acc, 8, 16); acc += __shfl_down(acc, 4, 16);
            acc += __shfl_down(acc, 2, 16); acc += __shfl_down(acc, 1, 16);
            if (sub == 0) lds[L_ES + sloc] = __expf(acc);  // |score|<=~20: fp32-safe
        }
        __syncthreads();
        {
            float l = 0.f;
#pragma unroll
            for (int i = 0; i < 16; ++i) l += lds[L_ES + i];
            const float invl = 1.f / l;
            float wp0 = 0.f, wp1 = 0.f;
            const float2* er = (const float2*)&enc[(b * 256 + s * 16) * 512];
#pragma unroll
            for (int sl = 0; sl < 16; ++sl) {
                const float2 e = er[sl * 256 + tid];
                const float es = lds[L_ES + sl];
                wp0 += es * e.x; wp1 += es * e.y;
            }
            // per-slice normalized: |wn| <= max|enc| -> f16-safe
            ucstore(&wnS[(b * 16 + s) * 256 + tid], packh2(wp0 * invl, wp1 * invl));
            if (tid == 0) cstore(&lS[b * 16 + s], l);
        }
        __syncthreads();
        if (tid == 0) ucstore(&tags[(b * 16 + s) * 32 + 1], tgt);
        if (tid < 16) {
            const unsigned* tg = &tags[(b * 16 + tid) * 32 + 1];
            while (ucload(tg) < tgt) __builtin_amdgcn_s_sleep(1);
            lds[L_LL + tid] = cload(&lS[b * 16 + tid]);  // own producer's L
        }
        __syncthreads();
        __builtin_amdgcn_fence(__ATOMIC_ACQUIRE, "workgroup");
        {
            float Lsum = 0.f;
#pragma unroll
            for (int i = 0; i < 16; ++i) Lsum += lds[L_LL + i];
            const float inv = 1.f / Lsum;
            float w0 = 0.f, w1 = 0.f;
#pragma unroll
            for (int sp = 0; sp < 16; ++sp) {
                U32H u; u.u = ucload(&wnS[(b * 16 + sp) * 256 + tid]);
                const float Ls = lds[L_LL + sp];
                w0 += Ls * (float)u.h.x; w1 += Ls * (float)u.h.y;
            }
            ldsU[L_HX + 4 + tid] = packh2(w0 * inv, w1 * inv);
            if (tid < 4)
                ldsU[L_HX + tid] = packh2(lds[L_XINL + 2 * tid], lds[L_XINL + 2 * tid + 1]);
        }
        __syncthreads();

        // ---- phase 2: GRU0 gate rows [s*32,+32) -> h0new slice ----
        if (tid < 192) {
            const int u = tid >> 1, sub = tid & 1;
            const int gh = u >> 5, r = u & 31;
            const int grow = gh * 512 + s * 32 + r;
            const uint4* wx = (const uint4*)&wih0U[grow * 260 + sub * 132];
            const uint4* xp = (const uint4*)&ldsU[L_HX + sub * 132];
            float ax = 0.f;
#pragma unroll 11
            for (int k4 = 0; k4 < 33; ++k4) {
                const uint4 xv = xp[k4], wv = wx[k4];
                ax = dot2(xv.x, wv.x, ax); ax = dot2(xv.y, wv.y, ax);
                ax = dot2(xv.z, wv.z, ax); ax = dot2(xv.w, wv.w, ax);
            }
            const uint4* wh = (const uint4*)&whh0U[grow * 256 + sub * 128];
            const uint4* hp = (const uint4*)&ldsU[L_H0 + sub * 128];
            float ah = 0.f;
#pragma unroll 8
            for (int k4 = 0; k4 < 32; ++k4) {
                const uint4 hv = hp[k4], wv = wh[k4];
                ah = dot2(hv.x, wv.x, ah); ah = dot2(hv.y, wv.y, ah);
                ah = dot2(hv.z, wv.z, ah); ah = dot2(hv.w, wv.w, ah);
            }
            ax += __shfl_down(ax, 1, 2); ah += __shfl_down(ah, 1, 2);
            if (sub == 0) {
                lds[L_AX + u] = ax + lds[L_BIH0 + u];
                lds[L_AH + u] = ah + lds[L_BHH0 + u];
            }
        }
        __syncthreads();
        if (tid < 32) {
            const int r = tid;
            const float rg = fsig(lds[L_AX + r] + lds[L_AH + r]);
            const float z = fsig(lds[L_AX + 32 + r] + lds[L_AH + 32 + r]);
            const float n = ftanhf(lds[L_AX + 64 + r] + rg * lds[L_AH + 64 + r]);
            U32H u; u.u = ldsU[L_H0 + s * 16 + (r >> 1)];
            const float hold = (r & 1) ? (float)u.h.y : (float)u.h.x;
            const float hs = (1.f - z) * n + z * hold;
            const float hsn = __shfl_down(hs, 1, 2);
            if ((r & 1) == 0)
                ucstore(&h0S[(b * 16 + s) * 16 + (r >> 1)], packh2(hs, hsn));
        }
        __syncthreads();
        if (tid == 0) ucstore(&tags[(b * 16 + s) * 32 + 2], tgt);
        if (tid < 16) {
            const unsigned* tg = &tags[(b * 16 + tid) * 32 + 2];
            while (ucload(tg) < tgt) __builtin_amdgcn_s_sleep(1);
        }
        __syncthreads();
        __builtin_amdgcn_fence(__ATOMIC_ACQUIRE, "workgroup");
        ldsU[L_H0 + tid] = ucload(&h0S[(b * 16 + (tid >> 4)) * 16 + (tid & 15)]);
        __syncthreads();

        // ---- phase 3: GRU1 gate rows [s*32,+32) -> h1new slice + hidP part ---
        if (tid < 192) {
            const int u = tid >> 1, sub = tid & 1;
            const int gh = u >> 5, r = u & 31;
            const int grow = gh * 512 + s * 32 + r;
            const uint4* wx = (const uint4*)&wih1U[grow * 256 + sub * 128];
            const uint4* xp = (const uint4*)&ldsU[L_H0 + sub * 128];
            float ax = 0.f;
#pragma unroll 8
            for (int k4 = 0; k4 < 32; ++k4) {
                const uint4 xv = xp[k4], wv = wx[k4];
                ax = dot2(xv.x, wv.x, ax); ax = dot2(xv.y, wv.y, ax);
                ax = dot2(xv.z, wv.z, ax); ax = dot2(xv.w, wv.w, ax);
            }
            const uint4* wh = (const uint4*)&whh1U[grow * 256 + sub * 128];
            const uint4* hp = (const uint4*)&ldsU[L_H1 + sub * 128];
            float ah = 0.f;
#pragma unroll 8
            for (int k4 = 0; k4 < 32; ++k4) {
                const uint4 hv = hp[k4], wv = wh[k4];
                ah = dot2(hv.x, wv.x, ah); ah = dot2(hv.y, wv.y, ah);
                ah = dot2(hv.z, wv.z, ah); ah = dot2(hv.w, wv.w, ah);
            }
            ax += __shfl_down(ax, 1, 2); ah += __shfl_down(ah, 1, 2);
            if (sub == 0) {
                lds[L_AX + u] = ax + lds[L_BIH1 + u];
                lds[L_AH + u] = ah + lds[L_BHH1 + u];
            }
        }
        __syncthreads();
        if (tid < 32) {
            const int r = tid;
            const float rg = fsig(lds[L_AX + r] + lds[L_AH + r]);
            const float z = fsig(lds[L_AX + 32 + r] + lds[L_AH + 32 + r]);
            const float n = ftanhf(lds[L_AX + 64 + r] + rg * lds[L_AH + 64 + r]);
            U32H u; u.u = ldsU[L_H1 + s * 16 + (r >> 1)];
            const float hold = (r & 1) ? (float)u.h.y : (float)u.h.x;
            const float hs = (1.f - z) * n + z * hold;
            const float hsn = __shfl_down(hs, 1, 2);
            if ((r & 1) == 0) {
                const unsigned pk = packh2(hs, hsn);
                ldsU[L_H1S + (r >> 1)] = pk;
                ucstore(&h1S[(b * 16 + s) * 16 + (r >> 1)], pk);
            }
        }
        __syncthreads();
        {
            // hidP partials from own h1new slice (whidT rows s*16..s*16+15)
            float p0 = 0.f, p1 = 0.f;
#pragma unroll
            for (int k = 0; k < 16; ++k) {
                const unsigned hp = ldsU[L_H1S + k];
                p0 = dot2(whidTU[(s * 16 + k) * 512 + tid], hp, p0);
                p1 = dot2(whidTU[(s * 16 + k) * 512 + 256 + tid], hp, p1);
            }
            cstore(&hPP[(b * 16 + s) * 512 + tid], p0);
            cstore(&hPP[(b * 16 + s) * 512 + 256 + tid], p1);
        }
        __syncthreads();
        if (tid == 0) ucstore(&tags[(b * 16 + s) * 32 + 3], tgt);
        if (tid < 16) {
            const unsigned* tg = &tags[(b * 16 + tid) * 32 + 3];
            while (ucload(tg) < tgt) __builtin_amdgcn_s_sleep(1);
        }
        __syncthreads();
        __builtin_amdgcn_fence(__ATOMIC_ACQUIRE, "workgroup");
        ldsU[L_H1 + tid] = ucload(&h1S[(b * 16 + (tid >> 4)) * 16 + (tid & 15)]);
        {
            float a0 = 0.f, a1 = 0.f;
#pragma unroll
            for (int sp = 0; sp < 16; ++sp) {
                a0 += cload(&hPP[(b * 16 + sp) * 512 + tid]);
                a1 += cload(&hPP[(b * 16 + sp) * 512 + 256 + tid]);
            }
            lds[L_HIDP + tid] = a0;
            lds[L_HIDP + 256 + tid] = a1;
        }
        __syncthreads();

        // ---- phase 4 (local): out = relu(outW.[h1new|weighted|xin]+b) --------
        {
            const int f = tid >> 5, l = tid & 31;
            const float* ow = &outW[f * 1032];
            float acc = 0.f;
#pragma unroll
            for (int i = 0; i < 8; ++i) {
                const int k2 = i * 32 + l;
                U32H u; u.u = ldsU[L_H1 + k2];
                acc += ow[2 * k2] * (float)u.h.x + ow[2 * k2 + 1] * (float)u.h.y;
            }
#pragma unroll
            for (int i = 0; i < 8; ++i) {
                const int k2 = i * 32 + l;
                U32H u; u.u = ldsU[L_HX + 4 + k2];
                acc += ow[512 + 2 * k2] * (float)u.h.x + ow[512 + 2 * k2 + 1] * (float)u.h.y;
            }
            if (l < 8) acc += ow[1024 + l] * lds[L_XINL + l];
            acc += __shfl_down(acc, 16, 32); acc += __shfl_down(acc, 8, 32);
            acc += __shfl_down(acc, 4, 32); acc += __shfl_down(acc, 2, 32);
            acc += __shfl_down(acc, 1, 32);
            if (l == 0) {
                const float o = fmaxf(acc + outBias[f], 0.f);
                lds[L_ES + f] = o;
                if (s == 0) out[b * 256 + t * 8 + f] = o;
            }
        }
        __syncthreads();
        if (tid < 8) lds[L_XINL + tid] = lds[L_ES + tid];
        __syncthreads();
    }
}

extern "C" void kernel_launch(void* const* d_in, const int* in_sizes, int n_in,
                              void* d_out, int out_size, void* d_ws, size_t ws_size,
                              hipStream_t stream) {
    (void)in_sizes; (void)n_in; (void)out_size; (void)ws_size;
    hipMemsetAsync(d_ws, 0, 32768, stream);  // zero tag region + grid counter
    decoder_kernel<<<NBLK, NTHR, 0, stream>>>(
        (const float*)d_in[0], (const float*)d_in[1], (const float*)d_in[2],
        (const float*)d_in[3], (const float*)d_in[4], (const float*)d_in[5],
        (const float*)d_in[6], (const float*)d_in[7], (const float*)d_in[8],
        (const float*)d_in[9], (const float*)d_in[10], (const float*)d_in[11],
        (const float*)d_in[12], (const float*)d_in[13], (const float*)d_in[14],
        (const float*)d_in[15], (float*)d_out, (float*)d_ws);
}

// Round 11
// 873.301 us; speedup vs baseline: 1.5257x; 1.5257x over previous
//
#include <hip/hip_runtime.h>

// DecoderWithAttention: B=16, T=32, F=8, S_ENC=256, H=512, L=2.
// R17 = R15 restored verbatim (proven 822us best: 256 blocks = 16 batches x
// 16 slices, 4 tag+payload syncs/step, 16-poller discipline, normalized f16
// attention partials, internal prologue) + ONE local tweak: prologue pack
// loops load weight pairs as float2 (dwordx2) instead of 2 scalar loads.
//
// Session evidence (R7-R16): per-sync cost ~4.5us is invariant across 5 sync
// mechanisms; sync-count reduction via redundant compute (R13) or linear
// partials (R14/R16) always costs more than the sync it saves; 4 syncs x
// ~4.5us + ~5us work is the communication floor of this decomposition.

namespace {
constexpr int NTHR = 256, NBLK = 256;

// ws u32/float offsets. memset covers [0, 32768) bytes.
// tags[(b*16+s)*32 + phase]; phases 0..3. grid counter at u32 8180.
constexpr int OFF_HIDPS = 8192;       // [256][32] f32 hidP slices
constexpr int OFF_WNS   = 16384;      // [256][256] u32 normalized wp f16x2
constexpr int OFF_LS    = 81920;      // [256] f32 per-slice L
constexpr int OFF_H0S   = 82176;      // [256][16] u32 h0new slices
constexpr int OFF_H1S   = 86272;      // [256][16] u32 h1new slices
constexpr int OFF_AEH   = 90368;      // [512][256] u32 attn_W[:,512:]
constexpr int OFF_WHID  = OFF_AEH + 131072;      // [512][256] u32
constexpr int OFF_WIH0  = OFF_WHID + 131072;     // [1536][260] u32
constexpr int OFF_WHH0  = OFF_WIH0 + 399360;     // [1536][256] u32
constexpr int OFF_WIH1  = OFF_WHH0 + 393216;
constexpr int OFF_WHH1  = OFF_WIH1 + 393216;
constexpr int OFF_ENCP  = OFF_WHH1 + 393216;     // [4096][256] u32
// end = 2,980,096 floats = 11.92 MB

// LDS float/u32 offsets. P2 prologue staging uses [0..8192).
constexpr int L_H1   = 0;      // [256] u32 h1(t) f16x2 full
constexpr int L_H0   = 256;    // [256] u32 h0(t) f16x2 full
constexpr int L_HIDP = 512;    // [512] f32
constexpr int L_ES   = 1024;   // [16] exp(score) (reused for out staging)
constexpr int L_HX   = 1040;   // [264] u32: xin(4) | weighted(256) | pad(4)
constexpr int L_AX   = 1304;   // [96]
constexpr int L_AH   = 1400;   // [96]
constexpr int L_BIH0 = 1496, L_BHH0 = 1592, L_BIH1 = 1688, L_BHH1 = 1784;  // [96]
constexpr int L_VW   = 1880;   // [512]
constexpr int L_XINL = 2392;   // [8]
constexpr int L_LL   = 2400;   // [16] gathered L_s
constexpr int LDS_FLOATS = 8192;
}  // namespace

typedef _Float16 h2 __attribute__((ext_vector_type(2)));
union U32H { unsigned u; h2 h; };

__device__ __forceinline__ float dot2(unsigned a, unsigned b, float acc) {
    U32H ua, ub; ua.u = a; ub.u = b;
#if __has_builtin(__builtin_amdgcn_fdot2)
    return __builtin_amdgcn_fdot2(ua.h, ub.h, acc, false);
#else
    return acc + (float)ua.h.x * (float)ub.h.x + (float)ua.h.y * (float)ub.h.y;
#endif
}
__device__ __forceinline__ unsigned packh2(float a, float b) {
    U32H u; u.h = h2{(_Float16)a, (_Float16)b}; return u.u;
}
__device__ __forceinline__ unsigned packf2(float2 v) {
    U32H u; u.h = h2{(_Float16)v.x, (_Float16)v.y}; return u.u;
}
__device__ __forceinline__ float fsig(float x) { return 1.0f / (1.0f + __expf(-x)); }
__device__ __forceinline__ float ftanhf(float x) {
    float e = __expf(2.0f * x);
    return 1.0f - 2.0f / (e + 1.0f);
}
// Uncached per-access comm ops (sc0 sc1 -> coherence point).
__device__ __forceinline__ float cload(const float* p) {
    return __hip_atomic_load(p, __ATOMIC_RELAXED, __HIP_MEMORY_SCOPE_SYSTEM);
}
__device__ __forceinline__ void cstore(float* p, float v) {
    __hip_atomic_store(p, v, __ATOMIC_RELAXED, __HIP_MEMORY_SCOPE_SYSTEM);
}
__device__ __forceinline__ unsigned ucload(const unsigned* p) {
    return __hip_atomic_load(p, __ATOMIC_RELAXED, __HIP_MEMORY_SCOPE_SYSTEM);
}
__device__ __forceinline__ void ucstore(unsigned* p, unsigned v) {
    __hip_atomic_store(p, v, __ATOMIC_RELAXED, __HIP_MEMORY_SCOPE_SYSTEM);
}

// Prologue barrier: one agent-scope wbl2 (release) / inv (acquire) per block.
__device__ __forceinline__ void bar_sync_flush(unsigned* cnt, unsigned target) {
    __syncthreads();
    if (threadIdx.x == 0) {
        __builtin_amdgcn_fence(__ATOMIC_RELEASE, "agent");
        __hip_atomic_fetch_add(cnt, 1u, __ATOMIC_RELAXED, __HIP_MEMORY_SCOPE_SYSTEM);
        while (__hip_atomic_load(cnt, __ATOMIC_RELAXED, __HIP_MEMORY_SCOPE_SYSTEM) < target)
            __builtin_amdgcn_s_sleep(8);
        __builtin_amdgcn_fence(__ATOMIC_ACQUIRE, "agent");
    }
    __syncthreads();
}

__global__ __launch_bounds__(NTHR) void decoder_kernel(
    const float* __restrict__ target, const float* __restrict__ hidden0,
    const float* __restrict__ enc, const float* __restrict__ attn_W,
    const float* __restrict__ attn_b, const float* __restrict__ v_w,
    const float* __restrict__ Wih0, const float* __restrict__ Whh0,
    const float* __restrict__ bih0, const float* __restrict__ bhh0,
    const float* __restrict__ Wih1, const float* __restrict__ Whh1,
    const float* __restrict__ bih1, const float* __restrict__ bhh1,
    const float* __restrict__ outW, const float* __restrict__ outBias,
    float* __restrict__ out, float* __restrict__ ws) {
    const int tid = threadIdx.x, bid = blockIdx.x;
    const int b = bid >> 4, s = bid & 15;   // group (batch) / slice
    unsigned* tags = (unsigned*)ws;
    unsigned* gridCnt = (unsigned*)ws + 8180;

    float* hidPS = ws + OFF_HIDPS;
    unsigned* wnS = (unsigned*)(ws + OFF_WNS);
    float* lS = ws + OFF_LS;
    unsigned* h0S = (unsigned*)(ws + OFF_H0S);
    unsigned* h1S = (unsigned*)(ws + OFF_H1S);
    unsigned* aehU  = (unsigned*)(ws + OFF_AEH);
    unsigned* whidU = (unsigned*)(ws + OFF_WHID);
    unsigned* wih0U = (unsigned*)(ws + OFF_WIH0);
    unsigned* whh0U = (unsigned*)(ws + OFF_WHH0);
    unsigned* wih1U = (unsigned*)(ws + OFF_WIH1);
    unsigned* whh1U = (unsigned*)(ws + OFF_WHH1);
    unsigned* encpU = (unsigned*)(ws + OFF_ENCP);

    __shared__ __align__(16) float lds[LDS_FLOATS];
    unsigned* ldsU = (unsigned*)lds;
    const int gtid = bid * NTHR + tid;

    // ===================== P1: f16 pack (float2 loads, plain stores) ==========
    {
        const float2* aw = (const float2*)attn_W;     // [512][512] float2 view
        for (int i = gtid; i < 131072; i += NBLK * NTHR) {
            const int jr = i >> 8, p = i & 255;
            aehU[i]  = packf2(aw[jr * 512 + 256 + p]);
            whidU[i] = packf2(aw[jr * 512 + p]);
        }
    }
    {
        const float2* w = (const float2*)Wih0;
        for (int i = gtid; i < 399360; i += NBLK * NTHR)
            wih0U[i] = packf2(w[i]);
    }
    {
        const float2* wa = (const float2*)Whh0;
        const float2* wb = (const float2*)Wih1;
        const float2* wc = (const float2*)Whh1;
        for (int i = gtid; i < 393216; i += NBLK * NTHR) {
            whh0U[i] = packf2(wa[i]);
            wih1U[i] = packf2(wb[i]);
            whh1U[i] = packf2(wc[i]);
        }
    }
    bar_sync_flush(gridCnt, NBLK);  // one wbl2/inv per block

    // ===================== P2: enc_proj for own (b, 16 s), raw f32 enc ========
    {
        for (int i = 0; i < 32; ++i) {
            const int idx = tid + i * 256;
            lds[idx] = enc[(b * 256 + s * 16) * 512 + idx];  // 16 s x 512
        }
        __syncthreads();
        float a0[16], a1[16];
        const float bb0 = attn_b[2 * tid], bb1 = attn_b[2 * tid + 1];
#pragma unroll
        for (int sl = 0; sl < 16; ++sl) { a0[sl] = bb0; a1[sl] = bb1; }
        const unsigned* w0 = &aehU[(2 * tid) * 256];
        const unsigned* w1 = &aehU[(2 * tid + 1) * 256];
        for (int p = 0; p < 256; ++p) {
            const unsigned ww0 = w0[p], ww1 = w1[p];
#pragma unroll
            for (int sl = 0; sl < 16; ++sl) {
                const unsigned epk = packh2(lds[sl * 512 + 2 * p], lds[sl * 512 + 2 * p + 1]);
                a0[sl] = dot2(epk, ww0, a0[sl]);
                a1[sl] = dot2(epk, ww1, a1[sl]);
            }
        }
        for (int sl = 0; sl < 16; ++sl)  // self-read only (plain, same-XCD L2)
            encpU[(b * 256 + s * 16 + sl) * 256 + tid] = packh2(a0[sl], a1[sl]);
        __syncthreads();
    }

    // ===================== P3: pin biases + v_w in LDS ========================
    if (tid < 96) {
        const int grow = (tid >> 5) * 512 + s * 32 + (tid & 31);
        lds[L_BIH0 + tid] = bih0[grow]; lds[L_BHH0 + tid] = bhh0[grow];
        lds[L_BIH1 + tid] = bih1[grow]; lds[L_BHH1 + tid] = bhh1[grow];
    }
    lds[L_VW + tid] = v_w[tid];
    lds[L_VW + 256 + tid] = v_w[256 + tid];
    __syncthreads();

    // initial state (t=0): h0/h1 full + x_in from target
    {
        const float2* h0p = (const float2*)hidden0;
        ldsU[L_H1 + tid] = packf2(h0p[4096 + b * 256 + tid]);
        ldsU[L_H0 + tid] = packf2(h0p[b * 256 + tid]);
    }
    if (tid < 8) lds[L_XINL + tid] = target[b * 256 + tid];
    if (tid < 4) ldsU[L_HX + 260 + tid] = 0u;  // permanent zero tail pad
    __syncthreads();

    // ===================== main recurrence (group-local, tag-polled) ==========
    for (int t = 0; t < 32; ++t) {
        const unsigned tgt = (unsigned)(t + 1);

        // ---- phase 0: hidP own rows [s*32,+32) ----
        {
            const int r = tid >> 3, sub = tid & 7;
            const uint4* wrow = (const uint4*)&whidU[(s * 32 + r) * 256 + sub * 32];
            const uint4* h1p = (const uint4*)&ldsU[L_H1 + sub * 32];
            float acc = 0.f;
#pragma unroll
            for (int k4 = 0; k4 < 8; ++k4) {
                const uint4 hv = h1p[k4], wv = wrow[k4];
                acc = dot2(hv.x, wv.x, acc); acc = dot2(hv.y, wv.y, acc);
                acc = dot2(hv.z, wv.z, acc); acc = dot2(hv.w, wv.w, acc);
            }
            acc += __shfl_down(acc, 4, 8); acc += __shfl_down(acc, 2, 8); acc += __shfl_down(acc, 1, 8);
            if (sub == 0) cstore(&hidPS[(b * 16 + s) * 32 + r], acc);
        }
        __syncthreads();                       // drains payload stores (all waves)
        if (tid == 0) ucstore(&tags[(b * 16 + s) * 32 + 0], tgt);
        if (tid < 16) {                        // 16 pollers only (poll storm fix)
            const unsigned* tg = &tags[(b * 16 + tid) * 32 + 0];
            while (ucload(tg) < tgt) __builtin_amdgcn_s_sleep(1);
        }
        __syncthreads();
        __builtin_amdgcn_fence(__ATOMIC_ACQUIRE, "workgroup");
        lds[L_HIDP + tid] = cload(&hidPS[(b * 16 + (tid >> 5)) * 32 + (tid & 31)]);
        lds[L_HIDP + 256 + tid] = cload(&hidPS[(b * 16 + 8 + (tid >> 5)) * 32 + (tid & 31)]);
        __syncthreads();

        // ---- phase 1: energy own 16 s + exp + NORMALIZED f16 wp + L ----
        {
            const int sloc = tid >> 4, sub = tid & 15;
            const unsigned* ep = &encpU[(b * 256 + s * 16 + sloc) * 256];
            float acc = 0.f;
#pragma unroll 4
            for (int k2 = 0; k2 < 16; ++k2) {
                const int p = k2 * 16 + sub;
                U32H u; u.u = ep[p];
                acc += lds[L_VW + 2 * p] * ftanhf((float)u.h.x + lds[L_HIDP + 2 * p]);
                acc += lds[L_VW + 2 * p + 1] * ftanhf((float)u.h.y + lds[L_HIDP + 2 * p + 1]);
            }
            acc += __shfl_down(acc, 8, 16); acc += __shfl_down(acc, 4, 16);
            acc += __shfl_down(acc, 2, 16); acc += __shfl_down(acc, 1, 16);
            if (sub == 0) lds[L_ES + sloc] = __expf(acc);  // |score|<=~20: fp32-safe
        }
        __syncthreads();
        {
            float l = 0.f;
#pragma unroll
            for (int i = 0; i < 16; ++i) l += lds[L_ES + i];
            const float invl = 1.f / l;
            float wp0 = 0.f, wp1 = 0.f;
            const float2* er = (const float2*)&enc[(b * 256 + s * 16) * 512];
#pragma unroll
            for (int sl = 0; sl < 16; ++sl) {
                const float2 e = er[sl * 256 + tid];
                const float es = lds[L_ES + sl];
                wp0 += es * e.x; wp1 += es * e.y;
            }
            // per-slice normalized: |wn| <= max|enc| -> f16-safe
            ucstore(&wnS[(b * 16 + s) * 256 + tid], packh2(wp0 * invl, wp1 * invl));
            if (tid == 0) cstore(&lS[b * 16 + s], l);
        }
        __syncthreads();
        if (tid == 0) ucstore(&tags[(b * 16 + s) * 32 + 1], tgt);
        if (tid < 16) {
            const unsigned* tg = &tags[(b * 16 + tid) * 32 + 1];
            while (ucload(tg) < tgt) __builtin_amdgcn_s_sleep(1);
            lds[L_LL + tid] = cload(&lS[b * 16 + tid]);  // own producer's L
        }
        __syncthreads();
        __builtin_amdgcn_fence(__ATOMIC_ACQUIRE, "workgroup");
        {
            float Lsum = 0.f;
#pragma unroll
            for (int i = 0; i < 16; ++i) Lsum += lds[L_LL + i];
            const float inv = 1.f / Lsum;
            float w0 = 0.f, w1 = 0.f;
#pragma unroll
            for (int sp = 0; sp < 16; ++sp) {
                U32H u; u.u = ucload(&wnS[(b * 16 + sp) * 256 + tid]);
                const float Ls = lds[L_LL + sp];
                w0 += Ls * (float)u.h.x; w1 += Ls * (float)u.h.y;
            }
            ldsU[L_HX + 4 + tid] = packh2(w0 * inv, w1 * inv);
            if (tid < 4)
                ldsU[L_HX + tid] = packh2(lds[L_XINL + 2 * tid], lds[L_XINL + 2 * tid + 1]);
        }
        __syncthreads();

        // ---- phase 2: GRU0 gate rows [s*32,+32) -> h0new slice ----
        if (tid < 192) {
            const int u = tid >> 1, sub = tid & 1;
            const int gh = u >> 5, r = u & 31;
            const int grow = gh * 512 + s * 32 + r;
            const uint4* wx = (const uint4*)&wih0U[grow * 260 + sub * 132];
            const uint4* xp = (const uint4*)&ldsU[L_HX + sub * 132];
            float ax = 0.f;
#pragma unroll 11
            for (int k4 = 0; k4 < 33; ++k4) {
                const uint4 xv = xp[k4], wv = wx[k4];
                ax = dot2(xv.x, wv.x, ax); ax = dot2(xv.y, wv.y, ax);
                ax = dot2(xv.z, wv.z, ax); ax = dot2(xv.w, wv.w, ax);
            }
            const uint4* wh = (const uint4*)&whh0U[grow * 256 + sub * 128];
            const uint4* hp = (const uint4*)&ldsU[L_H0 + sub * 128];
            float ah = 0.f;
#pragma unroll 8
            for (int k4 = 0; k4 < 32; ++k4) {
                const uint4 hv = hp[k4], wv = wh[k4];
                ah = dot2(hv.x, wv.x, ah); ah = dot2(hv.y, wv.y, ah);
                ah = dot2(hv.z, wv.z, ah); ah = dot2(hv.w, wv.w, ah);
            }
            ax += __shfl_down(ax, 1, 2); ah += __shfl_down(ah, 1, 2);
            if (sub == 0) {
                lds[L_AX + u] = ax + lds[L_BIH0 + u];
                lds[L_AH + u] = ah + lds[L_BHH0 + u];
            }
        }
        __syncthreads();
        if (tid < 32) {
            const int r = tid;
            const float rg = fsig(lds[L_AX + r] + lds[L_AH + r]);
            const float z = fsig(lds[L_AX + 32 + r] + lds[L_AH + 32 + r]);
            const float n = ftanhf(lds[L_AX + 64 + r] + rg * lds[L_AH + 64 + r]);
            U32H u; u.u = ldsU[L_H0 + s * 16 + (r >> 1)];
            const float hold = (r & 1) ? (float)u.h.y : (float)u.h.x;
            const float hs = (1.f - z) * n + z * hold;
            const float hsn = __shfl_down(hs, 1, 2);
            if ((r & 1) == 0)
                ucstore(&h0S[(b * 16 + s) * 16 + (r >> 1)], packh2(hs, hsn));
        }
        __syncthreads();
        if (tid == 0) ucstore(&tags[(b * 16 + s) * 32 + 2], tgt);
        if (tid < 16) {
            const unsigned* tg = &tags[(b * 16 + tid) * 32 + 2];
            while (ucload(tg) < tgt) __builtin_amdgcn_s_sleep(1);
        }
        __syncthreads();
        __builtin_amdgcn_fence(__ATOMIC_ACQUIRE, "workgroup");
        ldsU[L_H0 + tid] = ucload(&h0S[(b * 16 + (tid >> 4)) * 16 + (tid & 15)]);
        __syncthreads();

        // ---- phase 3: GRU1 gate rows [s*32,+32) -> h1new slice ----
        if (tid < 192) {
            const int u = tid >> 1, sub = tid & 1;
            const int gh = u >> 5, r = u & 31;
            const int grow = gh * 512 + s * 32 + r;
            const uint4* wx = (const uint4*)&wih1U[grow * 256 + sub * 128];
            const uint4* xp = (const uint4*)&ldsU[L_H0 + sub * 128];
            float ax = 0.f;
#pragma unroll 8
            for (int k4 = 0; k4 < 32; ++k4) {
                const uint4 xv = xp[k4], wv = wx[k4];
                ax = dot2(xv.x, wv.x, ax); ax = dot2(xv.y, wv.y, ax);
                ax = dot2(xv.z, wv.z, ax); ax = dot2(xv.w, wv.w, ax);
            }
            const uint4* wh = (const uint4*)&whh1U[grow * 256 + sub * 128];
            const uint4* hp = (const uint4*)&ldsU[L_H1 + sub * 128];
            float ah = 0.f;
#pragma unroll 8
            for (int k4 = 0; k4 < 32; ++k4) {
                const uint4 hv = hp[k4], wv = wh[k4];
                ah = dot2(hv.x, wv.x, ah); ah = dot2(hv.y, wv.y, ah);
                ah = dot2(hv.z, wv.z, ah); ah = dot2(hv.w, wv.w, ah);
            }
            ax += __shfl_down(ax, 1, 2); ah += __shfl_down(ah, 1, 2);
            if (sub == 0) {
                lds[L_AX + u] = ax + lds[L_BIH1 + u];
                lds[L_AH + u] = ah + lds[L_BHH1 + u];
            }
        }
        __syncthreads();
        if (tid < 32) {
            const int r = tid;
            const float rg = fsig(lds[L_AX + r] + lds[L_AH + r]);
            const float z = fsig(lds[L_AX + 32 + r] + lds[L_AH + 32 + r]);
            const float n = ftanhf(lds[L_AX + 64 + r] + rg * lds[L_AH + 64 + r]);
            U32H u; u.u = ldsU[L_H1 + s * 16 + (r >> 1)];
            const float hold = (r & 1) ? (float)u.h.y : (float)u.h.x;
            const float hs = (1.f - z) * n + z * hold;
            const float hsn = __shfl_down(hs, 1, 2);
            if ((r & 1) == 0)
                ucstore(&h1S[(b * 16 + s) * 16 + (r >> 1)], packh2(hs, hsn));
        }
        __syncthreads();
        if (tid == 0) ucstore(&tags[(b * 16 + s) * 32 + 3], tgt);
        if (tid < 16) {
            const unsigned* tg = &tags[(b * 16 + tid) * 32 + 3];
            while (ucload(tg) < tgt) __builtin_amdgcn_s_sleep(1);
        }
        __syncthreads();
        __builtin_amdgcn_fence(__ATOMIC_ACQUIRE, "workgroup");
        ldsU[L_H1 + tid] = ucload(&h1S[(b * 16 + (tid >> 4)) * 16 + (tid & 15)]);
        __syncthreads();

        // ---- phase 4 (local): out = relu(outW.[h1new|weighted|xin]+b) --------
        {
            const int f = tid >> 5, l = tid & 31;
            const float* ow = &outW[f * 1032];
            float acc = 0.f;
#pragma unroll
            for (int i = 0; i < 8; ++i) {
                const int k2 = i * 32 + l;
                U32H u; u.u = ldsU[L_H1 + k2];
                acc += ow[2 * k2] * (float)u.h.x + ow[2 * k2 + 1] * (float)u.h.y;
            }
#pragma unroll
            for (int i = 0; i < 8; ++i) {
                const int k2 = i * 32 + l;
                U32H u; u.u = ldsU[L_HX + 4 + k2];
                acc += ow[512 + 2 * k2] * (float)u.h.x + ow[512 + 2 * k2 + 1] * (float)u.h.y;
            }
            if (l < 8) acc += ow[1024 + l] * lds[L_XINL + l];
            acc += __shfl_down(acc, 16, 32); acc += __shfl_down(acc, 8, 32);
            acc += __shfl_down(acc, 4, 32); acc += __shfl_down(acc, 2, 32);
            acc += __shfl_down(acc, 1, 32);
            if (l == 0) {
                const float o = fmaxf(acc + outBias[f], 0.f);
                lds[L_ES + f] = o;
                if (s == 0) out[b * 256 + t * 8 + f] = o;
            }
        }
        __syncthreads();
        if (tid < 8) lds[L_XINL + tid] = lds[L_ES + tid];
        __syncthreads();
    }
}

extern "C" void kernel_launch(void* const* d_in, const int* in_sizes, int n_in,
                              void* d_out, int out_size, void* d_ws, size_t ws_size,
                              hipStream_t stream) {
    (void)in_sizes; (void)n_in; (void)out_size; (void)ws_size;
    hipMemsetAsync(d_ws, 0, 32768, stream);  // zero tag region + grid counter
    decoder_kernel<<<NBLK, NTHR, 0, stream>>>(
        (const float*)d_in[0], (const float*)d_in[1], (const float*)d_in[2],
        (const float*)d_in[3], (const float*)d_in[4], (const float*)d_in[5],
        (const float*)d_in[6], (const float*)d_in[7], (const float*)d_in[8],
        (const float*)d_in[9], (const float*)d_in[10], (const float*)d_in[11],
        (const float*)d_in[12], (const float*)d_in[13], (const float*)d_in[14],
        (const float*)d_in[15], (float*)d_out, (float*)d_ws);
}